// Round 7
// baseline (237.558 us; speedup 1.0000x reference)
//
#include <hip/hip_runtime.h>

#define F_IN    32768
#define HID     64
#define NB_OBJ  16
#define BATCH   64
#define N_AGENTS 4
#define N_ACT   13
#define NEG_SLOPE 0.01f

#define FC      64               // f-chunk width per K2 block
#define NCHUNK  (F_IN / FC)      // 512 split-K chunks

typedef float f32x4 __attribute__((ext_vector_type(4)));

// static scratch:
// g_s    [BATCH][F_IN]          = 8 MiB   (node-mean, already /16)
// g_part [NCHUNK][BATCH][HID]   = 8 MiB   (split-K partials)
__device__ float g_s[BATCH * F_IN];
__device__ float g_part[NCHUNK * BATCH * HID];

// ---------------------------------------------------------------------------
// K1: pure streaming node-mean. s[b][f] = (1/16) * sum_o u[b][o][f].
// grid = 2048, block = 256. Per wave-instruction: 1 KiB contiguous read.
// Nontemporal: u has zero reuse; avoid L3 pollution (and make repeat
// launches re-read HBM for this round's differencing measurement).
// ---------------------------------------------------------------------------
__global__ __launch_bounds__(256, 4)
void k_mean(const float* __restrict__ u) {
    const int t   = threadIdx.x;
    const int bid = blockIdx.x;
    const int b   = bid >> 5;                       // 32 blocks per batch
    const int fq  = (bid & 31) * 256 + t;           // float4 index in row
    const float* base = u + (size_t)b * (NB_OBJ * F_IN) + (size_t)fq * 4;

    f32x4 a0 = (f32x4)(0.f), a1 = (f32x4)(0.f);
    #pragma unroll
    for (int o = 0; o < NB_OBJ; o += 2) {
        a0 += __builtin_nontemporal_load(reinterpret_cast<const f32x4*>(base + (size_t)o * F_IN));
        a1 += __builtin_nontemporal_load(reinterpret_cast<const f32x4*>(base + (size_t)(o + 1) * F_IN));
    }
    f32x4 s = (a0 + a1) * (1.0f / (float)NB_OBJ);
    *reinterpret_cast<f32x4*>(g_s + (size_t)b * F_IN + (size_t)fq * 4) = s;
}

// ---------------------------------------------------------------------------
// K2: split-K GEMM chunk: part[blk][b][h] = sum_{f in chunk} s[b][f] w[f][h].
// grid = NCHUNK (512), block = 256 (4 waves). Identical to Round 6.
// ---------------------------------------------------------------------------
__global__ __launch_bounds__(256, 4)
void k_gemm(const float* __restrict__ w) {
    __shared__ float xbar[BATCH][FC + 4];   // row pitch 68 floats
    const int t    = threadIdx.x;
    const int blk  = blockIdx.x;
    const int f0   = blk * FC;
    const int lane = t & 63;
    const int wv   = t >> 6;                // 0..3

    // stage full 64x64 s tile: thread (b = t>>2, j = t&3) loads 4 float4s
    {
        const int b = t >> 2, j = t & 3;
        const float* sp = g_s + (size_t)b * F_IN + f0;
        #pragma unroll
        for (int q = 0; q < 4; ++q) {
            f32x4 v = *reinterpret_cast<const f32x4*>(sp + (j + 4 * q) * 4);
            *reinterpret_cast<f32x4*>(&xbar[b][(j + 4 * q) * 4]) = v;
        }
    }

    // w column slice: wreg[f] = w[(f0+f)*HID + lane]
    float wreg[FC];
    {
        const float* wp = w + (size_t)f0 * HID + lane;
        #pragma unroll
        for (int f = 0; f < FC; ++f) wreg[f] = wp[f * HID];
    }
    __syncthreads();

    // each wave computes 16 batches; lane = output h. xbar reads broadcast.
    {
        float* pout = g_part + (size_t)blk * (BATCH * HID) + lane;
        #pragma unroll
        for (int bb = 0; bb < 16; ++bb) {
            const int b = wv * 16 + bb;
            float acc = 0.f;
            #pragma unroll
            for (int fq = 0; fq < FC / 4; ++fq) {
                f32x4 xb = *reinterpret_cast<const f32x4*>(&xbar[b][fq * 4]);
                acc += xb.x * wreg[fq * 4 + 0];
                acc += xb.y * wreg[fq * 4 + 1];
                acc += xb.z * wreg[fq * 4 + 2];
                acc += xb.w * wreg[fq * 4 + 3];
            }
            pout[b * HID] = acc;
        }
    }
}

// ---------------------------------------------------------------------------
// K3: per-batch split-K reduction + heads + argmax gather. Identical to R6.
// ---------------------------------------------------------------------------
__global__ __launch_bounds__(512)
void k_tail(const float* __restrict__ gcn_b,
            const float* __restrict__ w1, const float* __restrict__ b1,
            const float* __restrict__ w2, const float* __restrict__ b2,
            const float* __restrict__ actions, float* __restrict__ out) {
    const int b = blockIdx.x;
    const int t = threadIdx.x;
    __shared__ float red[8][HID];
    __shared__ float pooled[HID];
    __shared__ float zbuf[N_AGENTS][HID];
    __shared__ float qbuf[N_AGENTS][N_ACT];

    // phase 1: pooled[h] = sum_k part[k][b][h] + gcn_b[h]
    {
        const int h  = t & 63;
        const int kg = t >> 6;   // 0..7
        const float* p = g_part + (size_t)(kg * 64) * (BATCH * HID)
                       + (size_t)b * HID + h;
        float acc = 0.f;
        #pragma unroll 16
        for (int i = 0; i < 64; ++i)
            acc += p[(size_t)i * (BATCH * HID)];
        red[kg][h] = acc;
    }
    __syncthreads();
    if (t < HID) {
        float acc = gcn_b[t];
        #pragma unroll
        for (int kg = 0; kg < 8; ++kg) acc += red[kg][t];
        pooled[t] = acc;
    }
    __syncthreads();

    // phase 2: z[a][k] = leaky(b1 + sum_h pooled[h] * w1[a][h][k])
    if (t < N_AGENTS * HID) {
        const int a = t >> 6, k = t & 63;
        const float* w1p = w1 + a * (HID * HID) + k;
        float acc = b1[a * HID + k];
        #pragma unroll
        for (int hh = 0; hh < HID; ++hh) acc += pooled[hh] * w1p[hh * HID];
        zbuf[a][k] = (acc >= 0.f) ? acc : NEG_SLOPE * acc;
    }
    __syncthreads();

    // phase 3: q[a][c] = b2 + sum_h z[a][h] * w2[a][h][c]
    if (t < N_AGENTS * N_ACT) {
        const int a = t / N_ACT, c = t % N_ACT;
        const float* w2p = w2 + a * (HID * N_ACT) + c;
        float acc = b2[a * N_ACT + c];
        #pragma unroll
        for (int hh = 0; hh < HID; ++hh) acc += zbuf[a][hh] * w2p[hh * N_ACT];
        qbuf[a][c] = acc;
    }
    __syncthreads();

    // phase 4: argmax over actions (first-max, matching jnp.argmax), gather
    if (t < N_AGENTS) {
        const float* ap = actions + ((size_t)t * BATCH + b) * N_ACT;
        int best = 0; float bv = ap[0];
        for (int c = 1; c < N_ACT; ++c) {
            float v = ap[c];
            if (v > bv) { bv = v; best = c; }
        }
        out[t * BATCH + b] = qbuf[t][best];
    }
}

extern "C" void kernel_launch(void* const* d_in, const int* in_sizes, int n_in,
                              void* d_out, int out_size, void* d_ws, size_t ws_size,
                              hipStream_t stream) {
    const float* u   = (const float*)d_in[0];
    // d_in[1] = binary_tensor: dead in the reference computation
    const float* act = (const float*)d_in[2];
    const float* gw  = (const float*)d_in[3];
    const float* gb  = (const float*)d_in[4];
    const float* w1  = (const float*)d_in[5];
    const float* b1  = (const float*)d_in[6];
    const float* w2  = (const float*)d_in[7];
    const float* b2  = (const float*)d_in[8];
    float* out = (float*)d_out;

    // MEASUREMENT ROUND: k_mean launched 9x (deterministic — each rewrite of
    // g_s is identical). k_mean_dur ~= (this_round_dur - 46.7us) / 8.
    for (int r = 0; r < 9; ++r)
        hipLaunchKernelGGL(k_mean, dim3(2048), dim3(256), 0, stream, u);
    hipLaunchKernelGGL(k_gemm, dim3(NCHUNK), dim3(256), 0, stream, gw);
    hipLaunchKernelGGL(k_tail, dim3(BATCH),  dim3(512), 0, stream,
                       gb, w1, b1, w2, b2, act, out);
}

// Round 8
// 143.442 us; speedup vs baseline: 1.6561x; 1.6561x over previous
//
#include <hip/hip_runtime.h>

#define F_IN    32768
#define HID     64
#define NB_OBJ  16
#define BATCH   64
#define N_AGENTS 4
#define N_ACT   13
#define NEG_SLOPE 0.01f

#define FC      64               // f-chunk width per K2 block
#define NCHUNK  (F_IN / FC)      // 512 split-K chunks

typedef float f32x4 __attribute__((ext_vector_type(4)));

// static scratch:
// g_s    [BATCH][F_IN]          = 8 MiB   (node-mean, already /16)
// g_part [NCHUNK][BATCH][HID]   = 8 MiB   (split-K partials)
__device__ float g_s[BATCH * F_IN];
__device__ float g_part[NCHUNK * BATCH * HID];

// ---------------------------------------------------------------------------
// K1: pure streaming node-mean — IDENTICAL to Round 6 (plain loads).
// ---------------------------------------------------------------------------
__global__ __launch_bounds__(256, 4)
void k_mean(const float* __restrict__ u) {
    const int t   = threadIdx.x;
    const int bid = blockIdx.x;
    const int b   = bid >> 5;                       // 32 blocks per batch
    const int fq  = (bid & 31) * 256 + t;           // float4 index in row
    const float* base = u + (size_t)b * (NB_OBJ * F_IN) + (size_t)fq * 4;

    f32x4 a0 = (f32x4)(0.f), a1 = (f32x4)(0.f);
    #pragma unroll
    for (int o = 0; o < NB_OBJ; o += 2) {
        a0 += *reinterpret_cast<const f32x4*>(base + (size_t)o * F_IN);
        a1 += *reinterpret_cast<const f32x4*>(base + (size_t)(o + 1) * F_IN);
    }
    f32x4 s = (a0 + a1) * (1.0f / (float)NB_OBJ);
    *reinterpret_cast<f32x4*>(g_s + (size_t)b * F_IN + (size_t)fq * 4) = s;
}

// ---------------------------------------------------------------------------
// K2: split-K GEMM chunk — IDENTICAL to Round 6.
// ---------------------------------------------------------------------------
__global__ __launch_bounds__(256, 4)
void k_gemm(const float* __restrict__ w) {
    __shared__ float xbar[BATCH][FC + 4];   // row pitch 68 floats
    const int t    = threadIdx.x;
    const int blk  = blockIdx.x;
    const int f0   = blk * FC;
    const int lane = t & 63;
    const int wv   = t >> 6;                // 0..3

    // stage full 64x64 s tile: thread (b = t>>2, j = t&3) loads 4 float4s
    {
        const int b = t >> 2, j = t & 3;
        const float* sp = g_s + (size_t)b * F_IN + f0;
        #pragma unroll
        for (int q = 0; q < 4; ++q) {
            f32x4 v = *reinterpret_cast<const f32x4*>(sp + (j + 4 * q) * 4);
            *reinterpret_cast<f32x4*>(&xbar[b][(j + 4 * q) * 4]) = v;
        }
    }

    // w column slice: wreg[f] = w[(f0+f)*HID + lane]
    float wreg[FC];
    {
        const float* wp = w + (size_t)f0 * HID + lane;
        #pragma unroll
        for (int f = 0; f < FC; ++f) wreg[f] = wp[f * HID];
    }
    __syncthreads();

    // each wave computes 16 batches; lane = output h. xbar reads broadcast.
    {
        float* pout = g_part + (size_t)blk * (BATCH * HID) + lane;
        #pragma unroll
        for (int bb = 0; bb < 16; ++bb) {
            const int b = wv * 16 + bb;
            float acc = 0.f;
            #pragma unroll
            for (int fq = 0; fq < FC / 4; ++fq) {
                f32x4 xb = *reinterpret_cast<const f32x4*>(&xbar[b][fq * 4]);
                acc += xb.x * wreg[fq * 4 + 0];
                acc += xb.y * wreg[fq * 4 + 1];
                acc += xb.z * wreg[fq * 4 + 2];
                acc += xb.w * wreg[fq * 4 + 3];
            }
            pout[b * HID] = acc;
        }
    }
}

// ---------------------------------------------------------------------------
// K3: per-batch split-K reduction + heads + argmax gather — IDENTICAL to R6.
// ---------------------------------------------------------------------------
__global__ __launch_bounds__(512)
void k_tail(const float* __restrict__ gcn_b,
            const float* __restrict__ w1, const float* __restrict__ b1,
            const float* __restrict__ w2, const float* __restrict__ b2,
            const float* __restrict__ actions, float* __restrict__ out) {
    const int b = blockIdx.x;
    const int t = threadIdx.x;
    __shared__ float red[8][HID];
    __shared__ float pooled[HID];
    __shared__ float zbuf[N_AGENTS][HID];
    __shared__ float qbuf[N_AGENTS][N_ACT];

    // phase 1: pooled[h] = sum_k part[k][b][h] + gcn_b[h]
    {
        const int h  = t & 63;
        const int kg = t >> 6;   // 0..7
        const float* p = g_part + (size_t)(kg * 64) * (BATCH * HID)
                       + (size_t)b * HID + h;
        float acc = 0.f;
        #pragma unroll 16
        for (int i = 0; i < 64; ++i)
            acc += p[(size_t)i * (BATCH * HID)];
        red[kg][h] = acc;
    }
    __syncthreads();
    if (t < HID) {
        float acc = gcn_b[t];
        #pragma unroll
        for (int kg = 0; kg < 8; ++kg) acc += red[kg][t];
        pooled[t] = acc;
    }
    __syncthreads();

    // phase 2: z[a][k] = leaky(b1 + sum_h pooled[h] * w1[a][h][k])
    if (t < N_AGENTS * HID) {
        const int a = t >> 6, k = t & 63;
        const float* w1p = w1 + a * (HID * HID) + k;
        float acc = b1[a * HID + k];
        #pragma unroll
        for (int hh = 0; hh < HID; ++hh) acc += pooled[hh] * w1p[hh * HID];
        zbuf[a][k] = (acc >= 0.f) ? acc : NEG_SLOPE * acc;
    }
    __syncthreads();

    // phase 3: q[a][c] = b2 + sum_h z[a][h] * w2[a][h][c]
    if (t < N_AGENTS * N_ACT) {
        const int a = t / N_ACT, c = t % N_ACT;
        const float* w2p = w2 + a * (HID * N_ACT) + c;
        float acc = b2[a * N_ACT + c];
        #pragma unroll
        for (int hh = 0; hh < HID; ++hh) acc += zbuf[a][hh] * w2p[hh * N_ACT];
        qbuf[a][c] = acc;
    }
    __syncthreads();

    // phase 4: argmax over actions (first-max, matching jnp.argmax), gather
    if (t < N_AGENTS) {
        const float* ap = actions + ((size_t)t * BATCH + b) * N_ACT;
        int best = 0; float bv = ap[0];
        for (int c = 1; c < N_ACT; ++c) {
            float v = ap[c];
            if (v > bv) { bv = v; best = c; }
        }
        out[t * BATCH + b] = qbuf[t][best];
    }
}

extern "C" void kernel_launch(void* const* d_in, const int* in_sizes, int n_in,
                              void* d_out, int out_size, void* d_ws, size_t ws_size,
                              hipStream_t stream) {
    const float* u   = (const float*)d_in[0];
    // d_in[1] = binary_tensor: dead in the reference computation
    const float* act = (const float*)d_in[2];
    const float* gw  = (const float*)d_in[3];
    const float* gb  = (const float*)d_in[4];
    const float* w1  = (const float*)d_in[5];
    const float* b1  = (const float*)d_in[6];
    const float* w2  = (const float*)d_in[7];
    const float* b2  = (const float*)d_in[8];
    float* out = (float*)d_out;

    // MEASUREMENT ROUND 2: k_gemm launched 9x (deterministic — rereads stable
    // g_s, rewrites identical partials). k_gemm+gap ~= (this_dur - 46.7) / 8.
    hipLaunchKernelGGL(k_mean, dim3(2048), dim3(256), 0, stream, u);
    for (int r = 0; r < 9; ++r)
        hipLaunchKernelGGL(k_gemm, dim3(NCHUNK), dim3(256), 0, stream, gw);
    hipLaunchKernelGGL(k_tail, dim3(BATCH), dim3(512), 0, stream,
                       gb, w1, b1, w2, b2, act, out);
}

// Round 9
// 54.149 us; speedup vs baseline: 4.3871x; 2.6490x over previous
//
#include <hip/hip_runtime.h>

#define F_IN    32768
#define HID     64
#define NB_OBJ  16
#define BATCH   64
#define N_AGENTS 4
#define N_ACT   13
#define NEG_SLOPE 0.01f

#define FCB     128              // f-range per k_gemm2 block (2 sub-chunks of 64)
#define NCHUNK  (F_IN / FCB)     // 256 split-K partials

typedef float f32x4 __attribute__((ext_vector_type(4)));

// static scratch:
// g_s    [BATCH][F_IN]          = 8 MiB  (node-mean, already /16)
// g_part [NCHUNK][BATCH][HID]   = 4 MiB  (split-K partials)
__device__ float g_s[BATCH * F_IN];
__device__ float g_part[NCHUNK * BATCH * HID];

// ---------------------------------------------------------------------------
// K1: pure streaming node-mean — measured at HBM roofline (~23.5us). Unchanged.
// ---------------------------------------------------------------------------
__global__ __launch_bounds__(256, 4)
void k_mean(const float* __restrict__ u) {
    const int t   = threadIdx.x;
    const int bid = blockIdx.x;
    const int b   = bid >> 5;                       // 32 blocks per batch
    const int fq  = (bid & 31) * 256 + t;           // float4 index in row
    const float* base = u + (size_t)b * (NB_OBJ * F_IN) + (size_t)fq * 4;

    f32x4 a0 = (f32x4)(0.f), a1 = (f32x4)(0.f);
    #pragma unroll
    for (int o = 0; o < NB_OBJ; o += 2) {
        a0 += *reinterpret_cast<const f32x4*>(base + (size_t)o * F_IN);
        a1 += *reinterpret_cast<const f32x4*>(base + (size_t)(o + 1) * F_IN);
    }
    f32x4 s = (a0 + a1) * (1.0f / (float)NB_OBJ);
    *reinterpret_cast<f32x4*>(g_s + (size_t)b * F_IN + (size_t)fq * 4) = s;
}

// ---------------------------------------------------------------------------
// K2: no-LDS, no-barrier split-K GEMM.
// grid = NCHUNK (256) x block 512 (8 waves). Wave wv owns batches wv*8..+7;
// lane = output h. x values are read at WAVE-UNIFORM addresses (wv made
// provably uniform via readfirstlane) -> scalar/broadcast loads on the
// SMEM/L1 path, no LDS broadcast bottleneck, no __syncthreads at all.
// Each block covers K=128 as 2 sub-chunks of 64 with carried accumulators.
// ---------------------------------------------------------------------------
__global__ __launch_bounds__(512, 2)
void k_gemm2(const float* __restrict__ w) {
    const int t    = threadIdx.x;
    const int blk  = blockIdx.x;          // output chunk id, 0..255
    const int f0   = blk * FCB;
    const int lane = t & 63;              // output h
    const int wv_u = __builtin_amdgcn_readfirstlane(t >> 6);  // uniform wave id

    float acc[8];
    #pragma unroll
    for (int bb = 0; bb < 8; ++bb) acc[bb] = 0.f;

    #pragma unroll
    for (int sc = 0; sc < 2; ++sc) {
        const int f0s = f0 + sc * 64;

        // w column slice for this sub-chunk: wreg[f] = w[(f0s+f)*HID + lane]
        float wreg[64];
        {
            const float* wp = w + (size_t)f0s * HID + lane;
            #pragma unroll
            for (int f = 0; f < 64; ++f) wreg[f] = wp[f * HID];
        }

        // fully unrolled so wreg/acc indices are compile-time constants
        #pragma unroll
        for (int fq = 0; fq < 16; ++fq) {
            #pragma unroll
            for (int bb = 0; bb < 8; ++bb) {
                const float* xp = g_s + (size_t)(wv_u * 8 + bb) * F_IN + f0s + fq * 4;
                f32x4 xv = *reinterpret_cast<const f32x4*>(xp);  // wave-uniform
                acc[bb] += xv.x * wreg[fq * 4 + 0] + xv.y * wreg[fq * 4 + 1]
                         + xv.z * wreg[fq * 4 + 2] + xv.w * wreg[fq * 4 + 3];
            }
        }
    }

    // store: per (wave, bb) a contiguous 256B row
    #pragma unroll
    for (int bb = 0; bb < 8; ++bb) {
        const int b = wv_u * 8 + bb;
        g_part[((size_t)blk * BATCH + b) * HID + lane] = acc[bb];
    }
}

// ---------------------------------------------------------------------------
// K3: per-batch split-K reduction (256 chunks, 4 MiB total, L2/L3-hot) +
// heads + argmax gather. grid = BATCH (64), block = 512 (8 waves).
// ---------------------------------------------------------------------------
__global__ __launch_bounds__(512)
void k_tail(const float* __restrict__ gcn_b,
            const float* __restrict__ w1, const float* __restrict__ b1,
            const float* __restrict__ w2, const float* __restrict__ b2,
            const float* __restrict__ actions, float* __restrict__ out) {
    const int b = blockIdx.x;
    const int t = threadIdx.x;
    __shared__ float red[8][HID];
    __shared__ float pooled[HID];
    __shared__ float zbuf[N_AGENTS][HID];
    __shared__ float qbuf[N_AGENTS][N_ACT];

    // phase 1: pooled[h] = sum_k part[k][b][h] + gcn_b[h]; kg sums 32 chunks
    {
        const int h  = t & 63;
        const int kg = t >> 6;   // 0..7
        const float* p = g_part + (size_t)(kg * 32) * (BATCH * HID)
                       + (size_t)b * HID + h;
        float acc = 0.f;
        #pragma unroll 8
        for (int i = 0; i < 32; ++i)
            acc += p[(size_t)i * (BATCH * HID)];
        red[kg][h] = acc;
    }
    __syncthreads();
    if (t < HID) {
        float acc = gcn_b[t];
        #pragma unroll
        for (int kg = 0; kg < 8; ++kg) acc += red[kg][t];
        pooled[t] = acc;
    }
    __syncthreads();

    // phase 2: z[a][k] = leaky(b1 + sum_h pooled[h] * w1[a][h][k])
    if (t < N_AGENTS * HID) {
        const int a = t >> 6, k = t & 63;
        const float* w1p = w1 + a * (HID * HID) + k;
        float acc = b1[a * HID + k];
        #pragma unroll
        for (int hh = 0; hh < HID; ++hh) acc += pooled[hh] * w1p[hh * HID];
        zbuf[a][k] = (acc >= 0.f) ? acc : NEG_SLOPE * acc;
    }
    __syncthreads();

    // phase 3: q[a][c] = b2 + sum_h z[a][h] * w2[a][h][c]
    if (t < N_AGENTS * N_ACT) {
        const int a = t / N_ACT, c = t % N_ACT;
        const float* w2p = w2 + a * (HID * N_ACT) + c;
        float acc = b2[a * N_ACT + c];
        #pragma unroll
        for (int hh = 0; hh < HID; ++hh) acc += zbuf[a][hh] * w2p[hh * N_ACT];
        qbuf[a][c] = acc;
    }
    __syncthreads();

    // phase 4: argmax over actions (first-max, matching jnp.argmax), gather
    if (t < N_AGENTS) {
        const float* ap = actions + ((size_t)t * BATCH + b) * N_ACT;
        int best = 0; float bv = ap[0];
        for (int c = 1; c < N_ACT; ++c) {
            float v = ap[c];
            if (v > bv) { bv = v; best = c; }
        }
        out[t * BATCH + b] = qbuf[t][best];
    }
}

extern "C" void kernel_launch(void* const* d_in, const int* in_sizes, int n_in,
                              void* d_out, int out_size, void* d_ws, size_t ws_size,
                              hipStream_t stream) {
    const float* u   = (const float*)d_in[0];
    // d_in[1] = binary_tensor: dead in the reference computation
    const float* act = (const float*)d_in[2];
    const float* gw  = (const float*)d_in[3];
    const float* gb  = (const float*)d_in[4];
    const float* w1  = (const float*)d_in[5];
    const float* b1  = (const float*)d_in[6];
    const float* w2  = (const float*)d_in[7];
    const float* b2  = (const float*)d_in[8];
    float* out = (float*)d_out;

    hipLaunchKernelGGL(k_mean,  dim3(2048),   dim3(256), 0, stream, u);
    hipLaunchKernelGGL(k_gemm2, dim3(NCHUNK), dim3(512), 0, stream, gw);
    hipLaunchKernelGGL(k_tail,  dim3(BATCH),  dim3(512), 0, stream,
                       gb, w1, b1, w2, b2, act, out);
}

// Round 10
// 37.408 us; speedup vs baseline: 6.3505x; 1.4475x over previous
//
#include <hip/hip_runtime.h>

#define F_IN    32768
#define HID     64
#define NB_OBJ  16
#define BATCH   64
#define N_AGENTS 4
#define N_ACT   13
#define NEG_SLOPE 0.01f

#define FC      64               // f-chunk width per fused block
#define NCHUNK  (F_IN / FC)      // 512 split-K chunks

typedef float f32x4 __attribute__((ext_vector_type(4)));

// static scratch:
// g_part [NCHUNK][BATCH][HID] = 8 MiB   (split-K partials)
// g_red  [4][BATCH][HID]      = 64 KiB  (stage-2 partials)
__device__ float g_part[NCHUNK * BATCH * HID];
__device__ float g_red[4 * BATCH * HID];

// ---------------------------------------------------------------------------
// K1: fused node-mean + partial GEMM (Round-3 kernel, measured ~28.5us).
// grid = NCHUNK (512), block = 512 (8 waves).
// ---------------------------------------------------------------------------
__global__ __launch_bounds__(512, 4)
void k_fused(const float* __restrict__ u, const float* __restrict__ w) {
    __shared__ float xbar[BATCH][FC + 4];   // row pitch 68 floats
    const int t    = threadIdx.x;
    const int blk  = blockIdx.x;
    const int f0   = blk * FC;
    const int lane = t & 63;
    const int wv   = t >> 6;                // 0..7

    // w column slice in registers: wreg[f] = w[(f0+f)*HID + lane]
    float wreg[FC];
    {
        const float* wp = w + (size_t)f0 * HID + lane;
        #pragma unroll
        for (int f = 0; f < FC; ++f) wreg[f] = wp[f * HID];
    }

    // step A: xbar[b][f] = (1/16) * sum_o u[b][o][f0+f]
    // thread (b = t>>3, j = t&7): per-instr 8 x 128 B contiguous segments.
    {
        const int b = t >> 3;
        const int j = t & 7;
        const float* up = u + (size_t)b * (NB_OBJ * F_IN) + f0 + j * 4;
        f32x4 a0 = (f32x4)(0.f);
        f32x4 a1 = (f32x4)(0.f);
        #pragma unroll
        for (int o = 0; o < NB_OBJ; ++o) {
            const float* ro = up + o * F_IN;
            a0 += *reinterpret_cast<const f32x4*>(ro);
            a1 += *reinterpret_cast<const f32x4*>(ro + 32);
        }
        const float inv = 1.0f / (float)NB_OBJ;
        a0 *= inv;
        a1 *= inv;
        *reinterpret_cast<f32x4*>(&xbar[b][j * 4])      = a0;
        *reinterpret_cast<f32x4*>(&xbar[b][32 + j * 4]) = a1;
    }
    __syncthreads();

    // step B: each wave -> 8 batches; lane = output h. xbar reads broadcast.
    {
        float* pout = g_part + (size_t)blk * (BATCH * HID) + lane;
        #pragma unroll
        for (int bb = 0; bb < 8; ++bb) {
            const int b = wv * 8 + bb;
            float acc = 0.f;
            #pragma unroll
            for (int fq = 0; fq < FC / 4; ++fq) {
                f32x4 xb = *reinterpret_cast<const f32x4*>(&xbar[b][fq * 4]);
                acc += xb.x * wreg[fq * 4 + 0];
                acc += xb.y * wreg[fq * 4 + 1];
                acc += xb.z * wreg[fq * 4 + 2];
                acc += xb.w * wreg[fq * 4 + 3];
            }
            pout[b * HID] = acc;
        }
    }
}

// ---------------------------------------------------------------------------
// T1: full-machine split-K reduction 512 -> 4. grid = 256 (b x quarter),
// block = 256. Per-instr 256 B coalesced; 32 loads fully unrolled (MLP).
// ---------------------------------------------------------------------------
__global__ __launch_bounds__(256)
void k_red() {
    __shared__ float red[4][HID];
    const int bid = blockIdx.x;
    const int b   = bid & 63;
    const int q   = bid >> 6;     // 0..3
    const int t   = threadIdx.x;
    const int h   = t & 63;
    const int i   = t >> 6;       // 0..3

    const float* p = g_part + (size_t)(q * 128 + i * 32) * (BATCH * HID)
                   + (size_t)b * HID + h;
    float acc = 0.f;
    #pragma unroll
    for (int k = 0; k < 32; ++k)
        acc += p[(size_t)k * (BATCH * HID)];
    red[i][h] = acc;
    __syncthreads();

    if (t < HID)
        g_red[((size_t)q * BATCH + b) * HID + t] =
            red[0][t] + red[1][t] + red[2][t] + red[3][t];
}

// ---------------------------------------------------------------------------
// T2: finish pooled + per-agent heads + argmax gather.
// grid = BATCH (64), block = 256.
// ---------------------------------------------------------------------------
__global__ __launch_bounds__(256)
void k_heads(const float* __restrict__ gcn_b,
             const float* __restrict__ w1, const float* __restrict__ b1,
             const float* __restrict__ w2, const float* __restrict__ b2,
             const float* __restrict__ actions, float* __restrict__ out) {
    const int b = blockIdx.x;
    const int t = threadIdx.x;
    __shared__ float pooled[HID];
    __shared__ float zbuf[N_AGENTS][HID];
    __shared__ float qbuf[N_AGENTS][N_ACT];

    if (t < HID) {
        pooled[t] = gcn_b[t]
                  + g_red[((size_t)0 * BATCH + b) * HID + t]
                  + g_red[((size_t)1 * BATCH + b) * HID + t]
                  + g_red[((size_t)2 * BATCH + b) * HID + t]
                  + g_red[((size_t)3 * BATCH + b) * HID + t];
    }
    __syncthreads();

    // z[a][k] = leaky(b1 + sum_h pooled[h] * w1[a][h][k])
    {
        const int a = t >> 6, k = t & 63;
        const float* w1p = w1 + a * (HID * HID) + k;
        float acc = b1[a * HID + k];
        #pragma unroll
        for (int hh = 0; hh < HID; ++hh) acc += pooled[hh] * w1p[hh * HID];
        zbuf[a][k] = (acc >= 0.f) ? acc : NEG_SLOPE * acc;
    }
    __syncthreads();

    // q[a][c] = b2 + sum_h z[a][h] * w2[a][h][c]
    if (t < N_AGENTS * N_ACT) {
        const int a = t / N_ACT, c = t % N_ACT;
        const float* w2p = w2 + a * (HID * N_ACT) + c;
        float acc = b2[a * N_ACT + c];
        #pragma unroll
        for (int hh = 0; hh < HID; ++hh) acc += zbuf[a][hh] * w2p[hh * N_ACT];
        qbuf[a][c] = acc;
    }
    __syncthreads();

    // argmax over actions (first-max, matching jnp.argmax), gather
    if (t < N_AGENTS) {
        const float* ap = actions + ((size_t)t * BATCH + b) * N_ACT;
        int best = 0; float bv = ap[0];
        for (int c = 1; c < N_ACT; ++c) {
            float v = ap[c];
            if (v > bv) { bv = v; best = c; }
        }
        out[t * BATCH + b] = qbuf[t][best];
    }
}

extern "C" void kernel_launch(void* const* d_in, const int* in_sizes, int n_in,
                              void* d_out, int out_size, void* d_ws, size_t ws_size,
                              hipStream_t stream) {
    const float* u   = (const float*)d_in[0];
    // d_in[1] = binary_tensor: dead in the reference computation
    const float* act = (const float*)d_in[2];
    const float* gw  = (const float*)d_in[3];
    const float* gb  = (const float*)d_in[4];
    const float* w1  = (const float*)d_in[5];
    const float* b1  = (const float*)d_in[6];
    const float* w2  = (const float*)d_in[7];
    const float* b2  = (const float*)d_in[8];
    float* out = (float*)d_out;

    hipLaunchKernelGGL(k_fused, dim3(NCHUNK), dim3(512), 0, stream, u, gw);
    hipLaunchKernelGGL(k_red,   dim3(256),    dim3(256), 0, stream);
    hipLaunchKernelGGL(k_heads, dim3(BATCH),  dim3(256), 0, stream,
                       gb, w1, b1, w2, b2, act, out);
}

// Round 11
// 36.172 us; speedup vs baseline: 6.5675x; 1.0342x over previous
//
#include <hip/hip_runtime.h>

#define F_IN    32768
#define HID     64
#define NB_OBJ  16
#define BATCH   64
#define N_AGENTS 4
#define N_ACT   13
#define NEG_SLOPE 0.01f

#define FC      64               // f-chunk width per fused block
#define NCHUNK  (F_IN / FC)      // 512 split-K chunks

typedef float f32x4 __attribute__((ext_vector_type(4)));

// static scratch: g_part[NCHUNK][BATCH][HID] = 8 MiB (split-K partials)
__device__ float g_part[NCHUNK * BATCH * HID];

// ---------------------------------------------------------------------------
// K1: fused node-mean + partial GEMM (Round-3/10 kernel, measured ~28.5us).
// grid = NCHUNK (512), block = 512 (8 waves). UNCHANGED.
// ---------------------------------------------------------------------------
__global__ __launch_bounds__(512, 4)
void k_fused(const float* __restrict__ u, const float* __restrict__ w) {
    __shared__ float xbar[BATCH][FC + 4];   // row pitch 68 floats
    const int t    = threadIdx.x;
    const int blk  = blockIdx.x;
    const int f0   = blk * FC;
    const int lane = t & 63;
    const int wv   = t >> 6;                // 0..7

    // w column slice in registers: wreg[f] = w[(f0+f)*HID + lane]
    float wreg[FC];
    {
        const float* wp = w + (size_t)f0 * HID + lane;
        #pragma unroll
        for (int f = 0; f < FC; ++f) wreg[f] = wp[f * HID];
    }

    // step A: xbar[b][f] = (1/16) * sum_o u[b][o][f0+f]
    {
        const int b = t >> 3;
        const int j = t & 7;
        const float* up = u + (size_t)b * (NB_OBJ * F_IN) + f0 + j * 4;
        f32x4 a0 = (f32x4)(0.f);
        f32x4 a1 = (f32x4)(0.f);
        #pragma unroll
        for (int o = 0; o < NB_OBJ; ++o) {
            const float* ro = up + o * F_IN;
            a0 += *reinterpret_cast<const f32x4*>(ro);
            a1 += *reinterpret_cast<const f32x4*>(ro + 32);
        }
        const float inv = 1.0f / (float)NB_OBJ;
        a0 *= inv;
        a1 *= inv;
        *reinterpret_cast<f32x4*>(&xbar[b][j * 4])      = a0;
        *reinterpret_cast<f32x4*>(&xbar[b][32 + j * 4]) = a1;
    }
    __syncthreads();

    // step B: each wave -> 8 batches; lane = output h. xbar reads broadcast.
    {
        float* pout = g_part + (size_t)blk * (BATCH * HID) + lane;
        #pragma unroll
        for (int bb = 0; bb < 8; ++bb) {
            const int b = wv * 8 + bb;
            float acc = 0.f;
            #pragma unroll
            for (int fq = 0; fq < FC / 4; ++fq) {
                f32x4 xb = *reinterpret_cast<const f32x4*>(&xbar[b][fq * 4]);
                acc += xb.x * wreg[fq * 4 + 0];
                acc += xb.y * wreg[fq * 4 + 1];
                acc += xb.z * wreg[fq * 4 + 2];
                acc += xb.w * wreg[fq * 4 + 3];
            }
            pout[b * HID] = acc;
        }
    }
}

// ---------------------------------------------------------------------------
// K2: single merged tail. grid = BATCH (64), block = 1024 (16 waves).
// phase 1: thread (kg = t>>6 in 0..15, h = t&63) sums 32 chunks with fully
// unrolled independent loads (256 B coalesced per wave-instr; 32-deep MLP
// x 16 waves to hide L3 latency). Then LDS-reduce + heads + argmax.
// ---------------------------------------------------------------------------
__global__ __launch_bounds__(1024)
void k_tail(const float* __restrict__ gcn_b,
            const float* __restrict__ w1, const float* __restrict__ b1,
            const float* __restrict__ w2, const float* __restrict__ b2,
            const float* __restrict__ actions, float* __restrict__ out) {
    const int b = blockIdx.x;
    const int t = threadIdx.x;
    __shared__ float red[16][HID];
    __shared__ float pooled[HID];
    __shared__ float zbuf[N_AGENTS][HID];
    __shared__ float qbuf[N_AGENTS][N_ACT];

    // phase 1: red[kg][h] = sum of this kg's 32 chunks
    {
        const int h  = t & 63;
        const int kg = t >> 6;   // 0..15
        const float* p = g_part + (size_t)(kg * 32) * (BATCH * HID)
                       + (size_t)b * HID + h;
        float acc = 0.f;
        #pragma unroll
        for (int i = 0; i < 32; ++i)
            acc += p[(size_t)i * (BATCH * HID)];
        red[kg][h] = acc;
    }
    __syncthreads();
    if (t < HID) {
        float acc = gcn_b[t];
        #pragma unroll
        for (int kg = 0; kg < 16; ++kg) acc += red[kg][t];
        pooled[t] = acc;
    }
    __syncthreads();

    // phase 2: z[a][k] = leaky(b1 + sum_h pooled[h] * w1[a][h][k])
    if (t < N_AGENTS * HID) {
        const int a = t >> 6, k = t & 63;
        const float* w1p = w1 + a * (HID * HID) + k;
        float acc = b1[a * HID + k];
        #pragma unroll
        for (int hh = 0; hh < HID; ++hh) acc += pooled[hh] * w1p[hh * HID];
        zbuf[a][k] = (acc >= 0.f) ? acc : NEG_SLOPE * acc;
    }
    __syncthreads();

    // phase 3: q[a][c] = b2 + sum_h z[a][h] * w2[a][h][c]
    if (t < N_AGENTS * N_ACT) {
        const int a = t / N_ACT, c = t % N_ACT;
        const float* w2p = w2 + a * (HID * N_ACT) + c;
        float acc = b2[a * N_ACT + c];
        #pragma unroll
        for (int hh = 0; hh < HID; ++hh) acc += zbuf[a][hh] * w2p[hh * N_ACT];
        qbuf[a][c] = acc;
    }
    __syncthreads();

    // phase 4: argmax over actions (first-max, matching jnp.argmax), gather
    if (t < N_AGENTS) {
        const float* ap = actions + ((size_t)t * BATCH + b) * N_ACT;
        int best = 0; float bv = ap[0];
        for (int c = 1; c < N_ACT; ++c) {
            float v = ap[c];
            if (v > bv) { bv = v; best = c; }
        }
        out[t * BATCH + b] = qbuf[t][best];
    }
}

extern "C" void kernel_launch(void* const* d_in, const int* in_sizes, int n_in,
                              void* d_out, int out_size, void* d_ws, size_t ws_size,
                              hipStream_t stream) {
    const float* u   = (const float*)d_in[0];
    // d_in[1] = binary_tensor: dead in the reference computation
    const float* act = (const float*)d_in[2];
    const float* gw  = (const float*)d_in[3];
    const float* gb  = (const float*)d_in[4];
    const float* w1  = (const float*)d_in[5];
    const float* b1  = (const float*)d_in[6];
    const float* w2  = (const float*)d_in[7];
    const float* b2  = (const float*)d_in[8];
    float* out = (float*)d_out;

    hipLaunchKernelGGL(k_fused, dim3(NCHUNK), dim3(512), 0, stream, u, gw);
    hipLaunchKernelGGL(k_tail,  dim3(BATCH),  dim3(1024), 0, stream,
                       gb, w1, b1, w2, b2, act, out);
}